// Round 3
// baseline (800.419 us; speedup 1.0000x reference)
//
#include <hip/hip_runtime.h>
#include <stdint.h>

typedef __attribute__((ext_vector_type(8))) short bf16x8;
typedef __attribute__((ext_vector_type(4))) float f32x4;

// d_ws weight pack (bf16 shorts), fragment f at short index f*512 + lane*8 + j:
//   f 0..23  : QKV  (nt = sel*4 + head, f = nt*2 + ks)
//   f 24..55 : W1   (f = 24 + nt*2 + ks)
//   f 56..87 : W2   (f = 56 + ksl*4 + nt)
//   f 88..95 : Wp   (f = 88 + nt*2 + ks)
// LDS: 8 per-wave arenas of 8832 B (identical internal layout to round 2):
//   +0 qS[16][68] (overlaid by sl0@0,sl1@1280 in MLP) +2176 kS +4352 vS +6528 hS[16][72]

static __device__ __forceinline__ unsigned short f2bf(float f) {
    unsigned int u = __float_as_uint(f);
    return (unsigned short)((u + 0x7FFFu + ((u >> 16) & 1u)) >> 16);
}
static __device__ __forceinline__ float bf2f(unsigned int b) {
    return __uint_as_float(b << 16);
}

// Per-wave phase fence: drain LDS ops, forbid compiler motion across (rule #18).
#define WSYNC() do { asm volatile("s_waitcnt lgkmcnt(0)" ::: "memory"); \
                     __builtin_amdgcn_sched_barrier(0); } while (0)

__global__ __launch_bounds__(512)
void pack_weights(const float* __restrict__ Wq, const float* __restrict__ Wk,
                  const float* __restrict__ Wv, const float* __restrict__ Wp,
                  const float* __restrict__ W1, const float* __restrict__ W2,
                  unsigned short* __restrict__ gw)
{
    int e  = blockIdx.x * 512 + threadIdx.x;   // e < 49152 exactly
    int j  = e & 7;
    int ln = (e >> 3) & 63;
    int f  = e >> 9;
    float src;
    if (f < 24) {                         // QKV: col = 16*(sel*4+h) + d
        int ks = f & 1, nt = f >> 1;
        int k = 8*(ln>>4) + j + 32*ks;
        int d = ln & 15, h = nt & 3, sel = nt >> 2;
        const float* W = (sel == 0) ? Wq : ((sel == 1) ? Wk : Wv);
        src = W[h*1024 + k*16 + d];
    } else if (f < 56) {                  // W1 [64 x 256]
        int t = f - 24; int ks = t & 1, nt = t >> 1;
        int k = 8*(ln>>4) + j + 32*ks;
        src = W1[k*256 + 16*nt + (ln & 15)];
    } else if (f < 88) {                  // W2 [256 x 64]
        int t = f - 56; int nt = t & 3, ksl = t >> 2;
        int k = 32*ksl + 8*(ln>>4) + j;
        src = W2[k*64 + 16*nt + (ln & 15)];
    } else {                              // Wp [64 x 64]
        int t = f - 88; int ks = t & 1, nt = t >> 1;
        int k = 8*(ln>>4) + j + 32*ks;
        src = Wp[k*64 + 16*nt + (ln & 15)];
    }
    gw[e] = f2bf(src);
}

__global__ __launch_bounds__(512, 4)
void fused_block(const unsigned short* __restrict__ gw,
                 const float* __restrict__ xg,
                 const float* __restrict__ bp, const float* __restrict__ b1,
                 const float* __restrict__ b2, const float* __restrict__ g1,
                 const float* __restrict__ be1, const float* __restrict__ g2,
                 const float* __restrict__ be2, float* __restrict__ out,
                 int nPairsTotal)
{
    __shared__ __align__(16) unsigned char LDS[70656];

    const int tid  = threadIdx.x;
    const int lane = tid & 63;
    const int wid  = tid >> 6;
    const int fr   = lane & 15;       // MFMA fragment row/col index
    const int fg   = lane >> 4;       // MFMA fragment k-group
    const int xr   = lane >> 2;       // x row owned by this lane (0..15)
    const int xc   = (lane & 3) * 16; // x col base

    // B-fragment fetch from global (L1/L2-resident stream)
    #define WFRAG(F) (*(const bf16x8*)(gw + (((F)*64 + lane) << 3)))

    // per-lane parameters
    float g1v[16], be1v[16], g2v[16], be2v[16];
    #pragma unroll
    for (int j = 0; j < 16; ++j) {
        int c = xc + j;
        g1v[j] = g1[c]; be1v[j] = be1[c]; g2v[j] = g2[c]; be2v[j] = be2[c];
    }
    float b1v[16], bpv[4], b2v[4];
    #pragma unroll
    for (int nt = 0; nt < 16; ++nt) b1v[nt] = b1[16*nt + fr];
    #pragma unroll
    for (int nt = 0; nt < 4; ++nt) { bpv[nt] = bp[16*nt + fr]; b2v[nt] = b2[16*nt + fr]; }

    unsigned char* arena = LDS + wid * 8832;
    unsigned short* qS  = (unsigned short*)(arena);
    unsigned short* kS  = (unsigned short*)(arena + 2176);
    unsigned short* vS  = (unsigned short*)(arena + 4352);
    unsigned short* hS  = (unsigned short*)(arena + 6528);
    unsigned short* sl0 = (unsigned short*)(arena);
    unsigned short* sl1 = (unsigned short*)(arena + 1280);

    const int pipe = blockIdx.x * 8 + wid;   // 512 blocks * 8 waves = 4096 pipes

    #pragma unroll 1
    for (int gp = pipe; gp < nPairsTotal; gp += 4096) {
        const float* xb = xg + (size_t)gp * 1024;
        float*       ob = out + (size_t)gp * 1024;

        f32x4 xv[4];
        #pragma unroll
        for (int i = 0; i < 4; ++i)
            xv[i] = *(const f32x4*)(xb + xr*64 + xc + 4*i);

        // ---- LN1 -> h (bf16) -> hS ----
        {
            float s = 0.f, ss = 0.f;
            #pragma unroll
            for (int i = 0; i < 4; ++i)
                #pragma unroll
                for (int j = 0; j < 4; ++j) { float v = xv[i][j]; s += v; ss += v*v; }
            s += __shfl_xor(s, 1, 64); ss += __shfl_xor(ss, 1, 64);
            s += __shfl_xor(s, 2, 64); ss += __shfl_xor(ss, 2, 64);
            float mu  = s * 0.015625f;
            float inv = rsqrtf(ss * 0.015625f - mu*mu + 1e-5f);
            #pragma unroll
            for (int i = 0; i < 4; ++i) {
                uint2 w;
                w.x = (unsigned)f2bf((xv[i][0]-mu)*inv*g1v[4*i+0] + be1v[4*i+0])
                    | ((unsigned)f2bf((xv[i][1]-mu)*inv*g1v[4*i+1] + be1v[4*i+1]) << 16);
                w.y = (unsigned)f2bf((xv[i][2]-mu)*inv*g1v[4*i+2] + be1v[4*i+2])
                    | ((unsigned)f2bf((xv[i][3]-mu)*inv*g1v[4*i+3] + be1v[4*i+3]) << 16);
                *((uint2*)(hS + xr*72 + xc + 4*i)) = w;
            }
        }
        WSYNC();

        // ---- QKV = h @ [Wq|Wk|Wv] ----
        {
            bf16x8 a0 = *(const bf16x8*)(hS + fr*72 + 8*fg);
            bf16x8 a1 = *(const bf16x8*)(hS + fr*72 + 8*fg + 32);
            #pragma unroll
            for (int nt = 0; nt < 12; ++nt) {
                bf16x8 u0 = WFRAG(nt*2+0);
                bf16x8 u1 = WFRAG(nt*2+1);
                f32x4 acc = {0.f, 0.f, 0.f, 0.f};
                acc = __builtin_amdgcn_mfma_f32_16x16x32_bf16(a0, u0, acc, 0, 0, 0);
                acc = __builtin_amdgcn_mfma_f32_16x16x32_bf16(a1, u1, acc, 0, 0, 0);
                unsigned short* dst = (nt < 4) ? qS : ((nt < 8) ? kS : vS);
                int c = 16*(nt & 3) + fr;
                #pragma unroll
                for (int r = 0; r < 4; ++r)
                    dst[(4*fg + r)*68 + c] = f2bf(acc[r]);     // D: col=fr, row=4*fg+r
            }
        }
        WSYNC();

        // ---- attention: lane = (pair-batch, head, tq) ----
        {
            int pb = lane >> 5, hd = (lane >> 3) & 3, tq = lane & 7;
            int qrow = 8*pb + tq;
            float qv[16];
            {
                const unsigned int* qp = (const unsigned int*)(qS + qrow*68 + 16*hd);
                #pragma unroll
                for (int u = 0; u < 8; ++u) {
                    unsigned int w = qp[u];
                    qv[2*u] = bf2f(w & 0xffffu); qv[2*u+1] = bf2f(w >> 16);
                }
            }
            float sc[8];
            #pragma unroll
            for (int tk = 0; tk < 8; ++tk) {
                const unsigned int* kp = (const unsigned int*)(kS + (8*pb + tk)*68 + 16*hd);
                float d = 0.f;
                #pragma unroll
                for (int u = 0; u < 8; ++u) {
                    unsigned int w = kp[u];
                    d += qv[2*u]*bf2f(w & 0xffffu) + qv[2*u+1]*bf2f(w >> 16);
                }
                sc[tk] = (tk <= tq) ? d * 0.125f : -1.0e30f;   // scale = C^-0.5
            }
            float mx = sc[0];
            #pragma unroll
            for (int tk = 1; tk < 8; ++tk) mx = fmaxf(mx, sc[tk]);
            float pw[8], ps = 0.f;
            #pragma unroll
            for (int tk = 0; tk < 8; ++tk) { pw[tk] = __expf(sc[tk] - mx); ps += pw[tk]; }
            float pinv = 1.f / ps;
            float av[16];
            #pragma unroll
            for (int j = 0; j < 16; ++j) av[j] = 0.f;
            #pragma unroll
            for (int tk = 0; tk < 8; ++tk) {
                float wgt = pw[tk];
                const unsigned int* vp = (const unsigned int*)(vS + (8*pb + tk)*68 + 16*hd);
                #pragma unroll
                for (int u = 0; u < 8; ++u) {
                    unsigned int w = vp[u];
                    av[2*u]   += wgt * bf2f(w & 0xffffu);
                    av[2*u+1] += wgt * bf2f(w >> 16);
                }
            }
            #pragma unroll
            for (int u = 0; u < 4; ++u) {
                uint2 w;
                w.x = (unsigned)f2bf(av[4*u+0]*pinv) | ((unsigned)f2bf(av[4*u+1]*pinv) << 16);
                w.y = (unsigned)f2bf(av[4*u+2]*pinv) | ((unsigned)f2bf(av[4*u+3]*pinv) << 16);
                *((uint2*)(hS + qrow*72 + 16*hd + 4*u)) = w;
            }
        }
        WSYNC();

        // ---- proj: sa = attn @ Wp + bp ----
        f32x4 sacc[4];
        {
            bf16x8 p0 = *(const bf16x8*)(hS + fr*72 + 8*fg);
            bf16x8 p1 = *(const bf16x8*)(hS + fr*72 + 8*fg + 32);
            #pragma unroll
            for (int nt = 0; nt < 4; ++nt) {
                bf16x8 w0 = WFRAG(88 + nt*2 + 0);
                bf16x8 w1 = WFRAG(88 + nt*2 + 1);
                f32x4 acc = {0.f,0.f,0.f,0.f};
                acc = __builtin_amdgcn_mfma_f32_16x16x32_bf16(p0, w0, acc, 0,0,0);
                acc = __builtin_amdgcn_mfma_f32_16x16x32_bf16(p1, w1, acc, 0,0,0);
                sacc[nt] = acc;
            }
        }
        WSYNC();                           // p-reads drained before hS overwrite
        #pragma unroll
        for (int nt = 0; nt < 4; ++nt)
            #pragma unroll
            for (int r = 0; r < 4; ++r)
                hS[(4*fg + r)*72 + 16*nt + fr] = f2bf(sacc[nt][r] + bpv[nt]);
        WSYNC();

        // ---- residual 1, then LN2 in-place ----
        #pragma unroll
        for (int i = 0; i < 4; ++i) {
            uint2 w = *((const uint2*)(hS + xr*72 + xc + 4*i));
            xv[i][0] += bf2f(w.x & 0xffffu); xv[i][1] += bf2f(w.x >> 16);
            xv[i][2] += bf2f(w.y & 0xffffu); xv[i][3] += bf2f(w.y >> 16);
        }
        {
            float s = 0.f, ss = 0.f;
            #pragma unroll
            for (int i = 0; i < 4; ++i)
                #pragma unroll
                for (int j = 0; j < 4; ++j) { float v = xv[i][j]; s += v; ss += v*v; }
            s += __shfl_xor(s, 1, 64); ss += __shfl_xor(ss, 1, 64);
            s += __shfl_xor(s, 2, 64); ss += __shfl_xor(ss, 2, 64);
            float mu  = s * 0.015625f;
            float inv = rsqrtf(ss * 0.015625f - mu*mu + 1e-5f);
            #pragma unroll
            for (int i = 0; i < 4; ++i) {
                uint2 w;
                w.x = (unsigned)f2bf((xv[i][0]-mu)*inv*g2v[4*i+0] + be2v[4*i+0])
                    | ((unsigned)f2bf((xv[i][1]-mu)*inv*g2v[4*i+1] + be2v[4*i+1]) << 16);
                w.y = (unsigned)f2bf((xv[i][2]-mu)*inv*g2v[4*i+2] + be2v[4*i+2])
                    | ((unsigned)f2bf((xv[i][3]-mu)*inv*g2v[4*i+3] + be2v[4*i+3]) << 16);
                *((uint2*)(hS + xr*72 + xc + 4*i)) = w;
            }
        }
        WSYNC();

        // ---- MLP ----
        bf16x8 c0 = *(const bf16x8*)(hS + fr*72 + 8*fg);
        bf16x8 c1 = *(const bf16x8*)(hS + fr*72 + 8*fg + 32);
        f32x4 ff[4];
        #pragma unroll
        for (int nt = 0; nt < 4; ++nt) { f32x4 z = {0.f,0.f,0.f,0.f}; ff[nt] = z; }
        #pragma unroll
        for (int np = 0; np < 8; ++np) {
            unsigned short* sl = (np & 1) ? sl1 : sl0;
            #pragma unroll
            for (int q = 0; q < 2; ++q) {
                int nt1 = 2*np + q;
                bf16x8 u0 = WFRAG(24 + nt1*2 + 0);
                bf16x8 u1 = WFRAG(24 + nt1*2 + 1);
                f32x4 acc = {0.f,0.f,0.f,0.f};
                acc = __builtin_amdgcn_mfma_f32_16x16x32_bf16(c0, u0, acc, 0,0,0);
                acc = __builtin_amdgcn_mfma_f32_16x16x32_bf16(c1, u1, acc, 0,0,0);
                #pragma unroll
                for (int r = 0; r < 4; ++r)
                    sl[(4*fg + r)*40 + 16*q + fr] = f2bf(fmaxf(acc[r] + b1v[nt1], 0.f));
            }
            WSYNC();
            bf16x8 as = *(const bf16x8*)(sl + fr*40 + 8*fg);
            #pragma unroll
            for (int nt2 = 0; nt2 < 4; ++nt2) {
                bf16x8 wb = WFRAG(56 + np*4 + nt2);
                ff[nt2] = __builtin_amdgcn_mfma_f32_16x16x32_bf16(as, wb, ff[nt2], 0,0,0);
            }
        }
        #pragma unroll
        for (int nt2 = 0; nt2 < 4; ++nt2)
            #pragma unroll
            for (int r = 0; r < 4; ++r)
                hS[(4*fg + r)*72 + 16*nt2 + fr] = f2bf(ff[nt2][r] + b2v[nt2]);
        WSYNC();

        // ---- residual 2 + store ----
        #pragma unroll
        for (int i = 0; i < 4; ++i) {
            uint2 w = *((const uint2*)(hS + xr*72 + xc + 4*i));
            f32x4 o = xv[i];
            o[0] += bf2f(w.x & 0xffffu); o[1] += bf2f(w.x >> 16);
            o[2] += bf2f(w.y & 0xffffu); o[3] += bf2f(w.y >> 16);
            *((f32x4*)(ob + xr*64 + xc + 4*i)) = o;
        }
        WSYNC();
    }
    #undef WFRAG
}

extern "C" void kernel_launch(void* const* d_in, const int* in_sizes, int n_in,
                              void* d_out, int out_size, void* d_ws, size_t ws_size,
                              hipStream_t stream) {
    const float* x   = (const float*)d_in[0];
    const float* Wq  = (const float*)d_in[1];
    const float* Wk  = (const float*)d_in[2];
    const float* Wv  = (const float*)d_in[3];
    const float* Wp  = (const float*)d_in[4];
    const float* bp  = (const float*)d_in[5];
    const float* W1  = (const float*)d_in[6];
    const float* b1  = (const float*)d_in[7];
    const float* W2  = (const float*)d_in[8];
    const float* b2  = (const float*)d_in[9];
    const float* g1  = (const float*)d_in[10];
    const float* be1 = (const float*)d_in[11];
    const float* g2  = (const float*)d_in[12];
    const float* be2 = (const float*)d_in[13];
    unsigned short* gw = (unsigned short*)d_ws;   // 49152 shorts = 96 KB

    pack_weights<<<dim3(96), dim3(512), 0, stream>>>(Wq, Wk, Wv, Wp, W1, W2, gw);

    int nPairs = in_sizes[0] / 1024;   // 32768
    fused_block<<<dim3(512), dim3(512), 0, stream>>>(
        gw, x, bp, b1, b2, g1, be1, g2, be2, (float*)d_out, nPairs);
}

// Round 4
// 147.335 us; speedup vs baseline: 5.4326x; 5.4326x over previous
//
#include <hip/hip_runtime.h>
#include <stdint.h>

typedef __attribute__((ext_vector_type(8))) short bf16x8;
typedef __attribute__((ext_vector_type(4))) float f32x4;

// LDS map (bytes):
//   [0, 90112)  weight B-fragments, bf16, frag f at short index f*512 + lane*8 + j
//     f 0..23: QKV (nt=sel*4+head, f=nt*2+ks)   f 24..55: W1 (f=24+nt*2+ks)
//     f 56..87: W2 (f=56+ksl*4+nt)              (Wp lives in VGPRs)
//   [90112, 157696) 8 per-wave arenas of 8448 B:
//     +0    qH [4 head][16 row][16 d]  (P overlays after scores; sl0/sl1 in MLP)
//     +2048 kH [4][16][16]
//     +4096 vT [4][16 d][16 tk]   (V transposed)
//     +6144 hS [16][72]           (h / attn-out / sa / h2 / ff bounce)

static __device__ __forceinline__ unsigned short f2bf(float f) {
    unsigned int u = __float_as_uint(f);
    return (unsigned short)((u + 0x7FFFu + ((u >> 16) & 1u)) >> 16);
}
static __device__ __forceinline__ float bf2f(unsigned int b) {
    return __uint_as_float(b << 16);
}

// Per-wave phase fence: drain LDS ops, forbid compiler motion across (rule #18).
#define WSYNC() do { asm volatile("s_waitcnt lgkmcnt(0)" ::: "memory"); \
                     __builtin_amdgcn_sched_barrier(0); } while (0)

__global__ __launch_bounds__(512, 2)
void fused_block(const float* __restrict__ xg,
                 const float* __restrict__ Wq, const float* __restrict__ Wk,
                 const float* __restrict__ Wv, const float* __restrict__ Wp,
                 const float* __restrict__ bp, const float* __restrict__ W1,
                 const float* __restrict__ b1, const float* __restrict__ W2,
                 const float* __restrict__ b2, const float* __restrict__ g1,
                 const float* __restrict__ be1, const float* __restrict__ g2,
                 const float* __restrict__ be2, float* __restrict__ out,
                 int nPairsTotal)
{
    __shared__ __align__(16) unsigned char LDS[157696];

    const int tid  = threadIdx.x;
    const int lane = tid & 63;
    const int wid  = tid >> 6;
    const int fr   = lane & 15;       // MFMA fragment row/col index
    const int fg   = lane >> 4;       // MFMA fragment k-group
    const int xr   = lane >> 2;       // x row owned by this lane (0..15)
    const int xc   = (lane & 3) * 16; // x col base

    // ---------------- weight preload into LDS (bf16 fragments) ----------------
    {
        unsigned short* lw = (unsigned short*)LDS;
        #pragma unroll 1
        for (int e = tid; e < 45056; e += 512) {
            int j  = e & 7;
            int ln = (e >> 3) & 63;
            float src;
            if (e < 12288) {                       // QKV: col = 16*(sel*4+h)+d
                int ks = (e >> 9) & 1, nt = e >> 10;
                int k = 8*(ln>>4) + j + 32*ks;
                int d = ln & 15, h = nt & 3, sel = nt >> 2;
                const float* W = (sel == 0) ? Wq : ((sel == 1) ? Wk : Wv);
                src = W[h*1024 + k*16 + d];
            } else if (e < 28672) {                // W1 [64 x 256]
                int t = e - 12288;
                int ks = (t >> 9) & 1, nt = t >> 10;
                int k = 8*(ln>>4) + j + 32*ks;
                src = W1[k*256 + 16*nt + (ln & 15)];
            } else {                               // W2 [256 x 64]
                int t = e - 28672;
                int nt = (t >> 9) & 3, ksl = t >> 11;
                int k = 32*ksl + 8*(ln>>4) + j;
                src = W2[k*64 + 16*nt + (ln & 15)];
            }
            lw[e] = f2bf(src);
        }
    }

    // Wp fragments in registers
    bf16x8 wpf[4][2];
    #pragma unroll
    for (int nt = 0; nt < 4; ++nt)
        #pragma unroll
        for (int ks = 0; ks < 2; ++ks) {
            bf16x8 v;
            #pragma unroll
            for (int j = 0; j < 8; ++j)
                v[j] = (short)f2bf(Wp[(8*fg + j + 32*ks)*64 + 16*nt + fr]);
            wpf[nt][ks] = v;
        }

    // per-lane parameters
    float g1v[16], be1v[16], g2v[16], be2v[16];
    #pragma unroll
    for (int j = 0; j < 16; ++j) {
        int c = xc + j;
        g1v[j] = g1[c]; be1v[j] = be1[c]; g2v[j] = g2[c]; be2v[j] = be2[c];
    }
    float b1v[16], bpv[4], b2v[4];
    #pragma unroll
    for (int nt = 0; nt < 16; ++nt) b1v[nt] = b1[16*nt + fr];
    #pragma unroll
    for (int nt = 0; nt < 4; ++nt) { bpv[nt] = bp[16*nt + fr]; b2v[nt] = b2[16*nt + fr]; }

    __syncthreads();

    unsigned char* arena = LDS + 90112 + wid * 8448;
    unsigned short* qH  = (unsigned short*)(arena);          // [4][16][16], P overlay
    unsigned short* kH  = (unsigned short*)(arena + 2048);   // [4][16][16]
    unsigned short* vT  = (unsigned short*)(arena + 4096);   // [4][16 d][16 tk]
    unsigned short* hS  = (unsigned short*)(arena + 6144);   // [16][72]
    unsigned short* sl0 = (unsigned short*)(arena);          // MLP slice dbuf
    unsigned short* sl1 = (unsigned short*)(arena + 1280);

    const int pipe = blockIdx.x * 8 + wid;   // 256 blocks * 8 waves = 2048 pipes

    const bf16x8 zero8 = {0,0,0,0,0,0,0,0};
    const short onebf = (short)0x3F80;
    const bf16x8 ones8 = {onebf,onebf,onebf,onebf,onebf,onebf,onebf,onebf};

    // prefetch first tile
    f32x4 xn[4];
    if (pipe < nPairsTotal) {
        const float* xb0 = xg + (size_t)pipe * 1024;
        #pragma unroll
        for (int i = 0; i < 4; ++i)
            xn[i] = *(const f32x4*)(xb0 + xr*64 + xc + 4*i);
    }

    #pragma unroll 1
    for (int gp = pipe; gp < nPairsTotal; gp += 2048) {
        float* ob = out + (size_t)gp * 1024;

        f32x4 xv[4];
        #pragma unroll
        for (int i = 0; i < 4; ++i) xv[i] = xn[i];

        // issue next-tile prefetch (stays in flight across the whole iteration)
        {
            int gpn = gp + 2048;
            if (gpn < nPairsTotal) {
                const float* xbn = xg + (size_t)gpn * 1024;
                #pragma unroll
                for (int i = 0; i < 4; ++i)
                    xn[i] = *(const f32x4*)(xbn + xr*64 + xc + 4*i);
            }
        }

        // ---- LN1 -> h (bf16) -> hS ----
        {
            float s = 0.f, ss = 0.f;
            #pragma unroll
            for (int i = 0; i < 4; ++i)
                #pragma unroll
                for (int j = 0; j < 4; ++j) { float v = xv[i][j]; s += v; ss += v*v; }
            s += __shfl_xor(s, 1, 64); ss += __shfl_xor(ss, 1, 64);
            s += __shfl_xor(s, 2, 64); ss += __shfl_xor(ss, 2, 64);
            float mu  = s * 0.015625f;
            float inv = rsqrtf(ss * 0.015625f - mu*mu + 1e-5f);
            #pragma unroll
            for (int i = 0; i < 4; ++i) {
                uint2 w;
                w.x = (unsigned)f2bf((xv[i][0]-mu)*inv*g1v[4*i+0] + be1v[4*i+0])
                    | ((unsigned)f2bf((xv[i][1]-mu)*inv*g1v[4*i+1] + be1v[4*i+1]) << 16);
                w.y = (unsigned)f2bf((xv[i][2]-mu)*inv*g1v[4*i+2] + be1v[4*i+2])
                    | ((unsigned)f2bf((xv[i][3]-mu)*inv*g1v[4*i+3] + be1v[4*i+3]) << 16);
                *((uint2*)(hS + xr*72 + xc + 4*i)) = w;
            }
        }
        WSYNC();

        // ---- QKV = h @ [Wq|Wk|Wv] -> qH/kH/vT per-head tiles ----
        {
            bf16x8 a0 = *(const bf16x8*)(hS + fr*72 + 8*fg);
            bf16x8 a1 = *(const bf16x8*)(hS + fr*72 + 8*fg + 32);
            #pragma unroll
            for (int nt = 0; nt < 12; ++nt) {
                bf16x8 u0 = *(const bf16x8*)(LDS + (((nt*2+0)*64 + lane) << 4));
                bf16x8 u1 = *(const bf16x8*)(LDS + (((nt*2+1)*64 + lane) << 4));
                f32x4 acc = {0.f, 0.f, 0.f, 0.f};
                acc = __builtin_amdgcn_mfma_f32_16x16x32_bf16(a0, u0, acc, 0, 0, 0);
                acc = __builtin_amdgcn_mfma_f32_16x16x32_bf16(a1, u1, acc, 0, 0, 0);
                int hd = nt & 3;
                if (nt < 4) {
                    #pragma unroll
                    for (int r = 0; r < 4; ++r)
                        qH[hd*256 + (4*fg + r)*16 + fr] = f2bf(acc[r]);
                } else if (nt < 8) {
                    #pragma unroll
                    for (int r = 0; r < 4; ++r)
                        kH[hd*256 + (4*fg + r)*16 + fr] = f2bf(acc[r]);
                } else {
                    #pragma unroll
                    for (int r = 0; r < 4; ++r)       // transposed: [d=fr][tk=4fg+r]
                        vT[hd*256 + fr*16 + (4*fg + r)] = f2bf(acc[r]);
                }
            }
        }
        WSYNC();

        // ---- attention scores + softmax (no max-sub; scores are tiny) ----
        // S_hd = Q_hd @ K_hd^T via one MFMA (K=32, upper half zero)
        #pragma unroll
        for (int hd = 0; hd < 4; ++hd) {
            bf16x8 qf = zero8, kf = zero8;
            if (fg < 2) {
                qf = *(const bf16x8*)(qH + hd*256 + fr*16 + 8*fg);
                kf = *(const bf16x8*)(kH + hd*256 + fr*16 + 8*fg);
            }
            f32x4 s = {0.f,0.f,0.f,0.f};
            s = __builtin_amdgcn_mfma_f32_16x16x32_bf16(qf, kf, s, 0, 0, 0);
            // D: lane holds S[row=4fg+r][tk=fr]; causal+batch mask, exp, store P
            #pragma unroll
            for (int r = 0; r < 4; ++r) {
                int row = 4*fg + r;
                bool valid = (((row ^ fr) & 8) == 0) && ((fr & 7) <= (row & 7));
                float e = valid ? __expf(s[r] * 0.125f) : 0.f;   // scale = C^-0.5
                qH[hd*256 + row*16 + fr] = f2bf(e);              // P overlays qH
            }
        }
        WSYNC();

        // ---- PV + row-sum (ones-MFMA) -> O -> hS ----
        #pragma unroll
        for (int hd = 0; hd < 4; ++hd) {
            bf16x8 pf = zero8, vf = zero8;
            if (fg < 2) {
                pf = *(const bf16x8*)(qH + hd*256 + fr*16 + 8*fg);
                vf = *(const bf16x8*)(vT + hd*256 + fr*16 + 8*fg);
            }
            f32x4 o  = {0.f,0.f,0.f,0.f};
            f32x4 rs = {0.f,0.f,0.f,0.f};
            o  = __builtin_amdgcn_mfma_f32_16x16x32_bf16(pf, vf,    o,  0, 0, 0);
            rs = __builtin_amdgcn_mfma_f32_16x16x32_bf16(pf, ones8, rs, 0, 0, 0);
            #pragma unroll
            for (int r = 0; r < 4; ++r) {
                float ov = o[r] * __builtin_amdgcn_rcpf(rs[r]);
                hS[(4*fg + r)*72 + 16*hd + fr] = f2bf(ov);
            }
        }
        WSYNC();

        // ---- proj: sa = attn @ Wp + bp ----
        f32x4 sacc[4];
        {
            bf16x8 p0 = *(const bf16x8*)(hS + fr*72 + 8*fg);
            bf16x8 p1 = *(const bf16x8*)(hS + fr*72 + 8*fg + 32);
            #pragma unroll
            for (int nt = 0; nt < 4; ++nt) {
                f32x4 acc = {0.f,0.f,0.f,0.f};
                acc = __builtin_amdgcn_mfma_f32_16x16x32_bf16(p0, wpf[nt][0], acc, 0,0,0);
                acc = __builtin_amdgcn_mfma_f32_16x16x32_bf16(p1, wpf[nt][1], acc, 0,0,0);
                sacc[nt] = acc;
            }
        }
        // stores depend on MFMA results -> cannot pass the p0/p1 reads
        #pragma unroll
        for (int nt = 0; nt < 4; ++nt)
            #pragma unroll
            for (int r = 0; r < 4; ++r)
                hS[(4*fg + r)*72 + 16*nt + fr] = f2bf(sacc[nt][r] + bpv[nt]);
        WSYNC();

        // ---- residual 1 (own cells), LN2 in-place ----
        #pragma unroll
        for (int i = 0; i < 4; ++i) {
            uint2 w = *((const uint2*)(hS + xr*72 + xc + 4*i));
            xv[i][0] += bf2f(w.x & 0xffffu); xv[i][1] += bf2f(w.x >> 16);
            xv[i][2] += bf2f(w.y & 0xffffu); xv[i][3] += bf2f(w.y >> 16);
        }
        {
            float s = 0.f, ss = 0.f;
            #pragma unroll
            for (int i = 0; i < 4; ++i)
                #pragma unroll
                for (int j = 0; j < 4; ++j) { float v = xv[i][j]; s += v; ss += v*v; }
            s += __shfl_xor(s, 1, 64); ss += __shfl_xor(ss, 1, 64);
            s += __shfl_xor(s, 2, 64); ss += __shfl_xor(ss, 2, 64);
            float mu  = s * 0.015625f;
            float inv = rsqrtf(ss * 0.015625f - mu*mu + 1e-5f);
            #pragma unroll
            for (int i = 0; i < 4; ++i) {
                uint2 w;
                w.x = (unsigned)f2bf((xv[i][0]-mu)*inv*g2v[4*i+0] + be2v[4*i+0])
                    | ((unsigned)f2bf((xv[i][1]-mu)*inv*g2v[4*i+1] + be2v[4*i+1]) << 16);
                w.y = (unsigned)f2bf((xv[i][2]-mu)*inv*g2v[4*i+2] + be2v[4*i+2])
                    | ((unsigned)f2bf((xv[i][3]-mu)*inv*g2v[4*i+3] + be2v[4*i+3]) << 16);
                *((uint2*)(hS + xr*72 + xc + 4*i)) = w;
            }
        }
        WSYNC();

        // ---- MLP ----
        bf16x8 c0 = *(const bf16x8*)(hS + fr*72 + 8*fg);
        bf16x8 c1 = *(const bf16x8*)(hS + fr*72 + 8*fg + 32);
        f32x4 ff[4];
        #pragma unroll
        for (int nt = 0; nt < 4; ++nt) { f32x4 z = {0.f,0.f,0.f,0.f}; ff[nt] = z; }
        #pragma unroll
        for (int np = 0; np < 8; ++np) {
            unsigned short* sl = (np & 1) ? sl1 : sl0;
            #pragma unroll
            for (int q = 0; q < 2; ++q) {
                int nt1 = 2*np + q;
                bf16x8 u0 = *(const bf16x8*)(LDS + 24576 + (((nt1*2+0)*64 + lane) << 4));
                bf16x8 u1 = *(const bf16x8*)(LDS + 24576 + (((nt1*2+1)*64 + lane) << 4));
                f32x4 acc = {0.f,0.f,0.f,0.f};
                acc = __builtin_amdgcn_mfma_f32_16x16x32_bf16(c0, u0, acc, 0,0,0);
                acc = __builtin_amdgcn_mfma_f32_16x16x32_bf16(c1, u1, acc, 0,0,0);
                #pragma unroll
                for (int r = 0; r < 4; ++r)
                    sl[(4*fg + r)*40 + 16*q + fr] = f2bf(fmaxf(acc[r] + b1v[nt1], 0.f));
            }
            WSYNC();
            bf16x8 as = *(const bf16x8*)(sl + fr*40 + 8*fg);
            #pragma unroll
            for (int nt2 = 0; nt2 < 4; ++nt2) {
                bf16x8 wb = *(const bf16x8*)(LDS + 57344 + (((np*4 + nt2)*64 + lane) << 4));
                ff[nt2] = __builtin_amdgcn_mfma_f32_16x16x32_bf16(as, wb, ff[nt2], 0,0,0);
            }
        }
        #pragma unroll
        for (int nt2 = 0; nt2 < 4; ++nt2)
            #pragma unroll
            for (int r = 0; r < 4; ++r)
                hS[(4*fg + r)*72 + 16*nt2 + fr] = f2bf(ff[nt2][r] + b2v[nt2]);
        WSYNC();

        // ---- residual 2 + store ----
        #pragma unroll
        for (int i = 0; i < 4; ++i) {
            uint2 w = *((const uint2*)(hS + xr*72 + xc + 4*i));
            f32x4 o = xv[i];
            o[0] += bf2f(w.x & 0xffffu); o[1] += bf2f(w.x >> 16);
            o[2] += bf2f(w.y & 0xffffu); o[3] += bf2f(w.y >> 16);
            *((f32x4*)(ob + xr*64 + xc + 4*i)) = o;
        }
        WSYNC();   // hS WAW fence vs next iteration's LN1 stores
    }
}

extern "C" void kernel_launch(void* const* d_in, const int* in_sizes, int n_in,
                              void* d_out, int out_size, void* d_ws, size_t ws_size,
                              hipStream_t stream) {
    const float* x   = (const float*)d_in[0];
    const float* Wq  = (const float*)d_in[1];
    const float* Wk  = (const float*)d_in[2];
    const float* Wv  = (const float*)d_in[3];
    const float* Wp  = (const float*)d_in[4];
    const float* bp  = (const float*)d_in[5];
    const float* W1  = (const float*)d_in[6];
    const float* b1  = (const float*)d_in[7];
    const float* W2  = (const float*)d_in[8];
    const float* b2  = (const float*)d_in[9];
    const float* g1  = (const float*)d_in[10];
    const float* be1 = (const float*)d_in[11];
    const float* g2  = (const float*)d_in[12];
    const float* be2 = (const float*)d_in[13];
    int nPairs = in_sizes[0] / 1024;   // (B*T*C) / (2*8*64) = 32768
    fused_block<<<dim3(256), dim3(512), 0, stream>>>(
        x, Wq, Wk, Wv, Wp, bp, W1, b1, W2, b2, g1, be1, g2, be2,
        (float*)d_out, nPairs);
}